// Round 5
// baseline (3273.207 us; speedup 1.0000x reference)
//
#include <hip/hip_runtime.h>
#include <stdint.h>

#define N_NODES 100000
#define N_EDGES 300000
#define D_IN 256
#define HID 1024
#define N_CLASSES 64
#define CM 12500      // row chunk for GEMM phases (8 chunks)
#define NCHUNK 8

typedef __bf16 bf16x8 __attribute__((ext_vector_type(8)));
typedef float f32x4 __attribute__((ext_vector_type(4)));

__device__ __forceinline__ float bf2f(unsigned short u) {
  union { unsigned int i; float f; } v; v.i = ((unsigned int)u) << 16; return v.f;
}
__device__ __forceinline__ unsigned short f2bf(float f) {
  union { float f; unsigned int i; } v; v.f = f;
  unsigned int u = v.i;
  unsigned int r = (u + 0x7FFFu + ((u >> 16) & 1u)) >> 16;  // RNE
  return (unsigned short)r;
}

// async global->LDS, 16B per lane; LDS dest must be wave-uniform base
__device__ __forceinline__ void async16(const void* g, void* l) {
  __builtin_amdgcn_global_load_lds(
      (const __attribute__((address_space(1))) void*)g,
      (__attribute__((address_space(3))) void*)l, 16, 0, 0);
}

// ---------------------------------------------------------------------------
// dtype probe: flags[0]=1 if float tensors are f32 (vs bf16),
//              flags[1]=1 if edge_index is int64 (vs int32).
// ---------------------------------------------------------------------------
__global__ void probe_flags(const unsigned short* __restrict__ w,
                            const unsigned int* __restrict__ e,
                            int* __restrict__ flags) {
  __shared__ int cnt;
  __shared__ unsigned int orv;
  if (threadIdx.x == 0) { cnt = 0; orv = 0u; }
  __syncthreads();
  int c = 0;
  for (int i = threadIdx.x; i < 4096; i += 256) {
    unsigned int ex = (w[i] >> 7) & 0xFFu;
    if (ex > 123u) ++c;
  }
  atomicAdd(&cnt, c);
  unsigned int o = 0;
  for (int j = threadIdx.x; j < 1000; j += 256) o |= e[2 * j + 1];
  atomicOr(&orv, o);
  __syncthreads();
  if (threadIdx.x == 0) {
    flags[0] = (cnt > 64) ? 1 : 0;
    flags[1] = (orv == 0u) ? 1 : 0;
  }
}

// extract src/dst as int32 regardless of input width
__global__ void cvt_edges(const unsigned int* __restrict__ ei,
                          int* __restrict__ src32, int* __restrict__ dst32,
                          const int* __restrict__ flags) {
  int i = blockIdx.x * 256 + threadIdx.x;
  if (i >= N_EDGES) return;
  if (flags[1]) {  // int64: (2,N_EDGES) of 64-bit -> low words
    src32[i] = (int)ei[2 * i];
    dst32[i] = (int)ei[2 * (size_t)N_EDGES + 2 * i];
  } else {
    src32[i] = (int)ei[i];
    dst32[i] = (int)ei[N_EDGES + i];
  }
}

// Wt[n][k] = bf16(W[k][n]) with dtype dispatch
__global__ void transpose_dual(const void* __restrict__ W,
                               unsigned short* __restrict__ Wt, int K, int N,
                               const int* __restrict__ flags) {
  long idx = (long)blockIdx.x * 256 + threadIdx.x;
  if (idx < (long)K * N) {
    int k = (int)(idx / N), n = (int)(idx % N);
    unsigned short v = flags[0] ? f2bf(((const float*)W)[idx])
                                : ((const unsigned short*)W)[idx];
    Wt[(long)n * K + k] = v;
  }
}

__global__ void cvt_bias(const void* __restrict__ b,
                         unsigned short* __restrict__ bb, int n,
                         const int* __restrict__ flags) {
  int i = blockIdx.x * 256 + threadIdx.x;
  if (i < n)
    bb[i] = flags[0] ? f2bf(((const float*)b)[i]) : ((const unsigned short*)b)[i];
}

// ---------------------------------------------------------------------------
// GEMM: C[M,N] = A[M,K] @ Bt[N,K]^T + bias(bf16), optional relu.
// 256 threads = 4 waves (WGM x WGN), each wave 64x64 via 4x4
// mfma_f32_16x16x32_bf16. BK=64. LDS XOR-swizzled in 16B chunks
// (LDS chunk c of row r holds global chunk c^(r&7)).
// EPI: 0 = bf16 store, 1 = relu + bf16 store, 2 = f32 store.
// ---------------------------------------------------------------------------
template <int WGM, int WGN, int EPI>
__global__ __launch_bounds__(256, 2) void gemm_bt(
    const unsigned short* __restrict__ A, const unsigned short* __restrict__ Bt,
    const unsigned short* __restrict__ bias, void* __restrict__ Cout,
    int M, int N, int K) {
  constexpr int BM = WGM * 64;
  constexpr int BN = WGN * 64;
  __shared__ alignas(16) unsigned short ldsA[BM * 64];
  __shared__ alignas(16) unsigned short ldsB[BN * 64];
  const int tid = threadIdx.x;
  const int lane = tid & 63;
  const int w = tid >> 6;
  const int wm = w % WGM;
  const int wn = w / WGM;
  const long row0 = (long)blockIdx.x * BM;
  const long col0 = (long)blockIdx.y * BN;
  const int l15 = lane & 15, lq = lane >> 4;

  f32x4 acc[4][4];
#pragma unroll
  for (int i = 0; i < 4; ++i)
#pragma unroll
    for (int j = 0; j < 4; ++j) acc[i][j] = f32x4{0.f, 0.f, 0.f, 0.f};

  for (int k0 = 0; k0 < K; k0 += 64) {
    // ---- stage A tile [BM][64] ----
#pragma unroll
    for (int i = 0; i < BM * 8 / 256; ++i) {
      int t = i * 256 + tid;
      int r = t >> 3, c = t & 7;
      long gr = row0 + r;
      if (gr >= M) gr = M - 1;  // clamp: rows past M unused in epilogue
      const unsigned short* g = A + gr * (long)K + k0 + ((c ^ (r & 7)) << 3);
      void* l = (char*)ldsA + (size_t)(i * 256 + (tid & ~63)) * 16;
      async16(g, l);
    }
    // ---- stage B tile [BN][64] ----
#pragma unroll
    for (int i = 0; i < BN * 8 / 256; ++i) {
      int t = i * 256 + tid;
      int r = t >> 3, c = t & 7;
      long gr = col0 + r;  // always < N (N % BN == 0 here)
      const unsigned short* g = Bt + gr * (long)K + k0 + ((c ^ (r & 7)) << 3);
      void* l = (char*)ldsB + (size_t)(i * 256 + (tid & ~63)) * 16;
      async16(g, l);
    }
    __syncthreads();
#pragma unroll
    for (int kk = 0; kk < 64; kk += 32) {
      bf16x8 av[4], bv[4];
#pragma unroll
      for (int mt = 0; mt < 4; ++mt) {
        int m = wm * 64 + mt * 16 + l15;
        int jj = ((kk >> 3) + lq) ^ (m & 7);
        av[mt] = *(const bf16x8*)(ldsA + m * 64 + jj * 8);
      }
#pragma unroll
      for (int nt = 0; nt < 4; ++nt) {
        int n = wn * 64 + nt * 16 + l15;
        int jj = ((kk >> 3) + lq) ^ (n & 7);
        bv[nt] = *(const bf16x8*)(ldsB + n * 64 + jj * 8);
      }
#pragma unroll
      for (int mt = 0; mt < 4; ++mt)
#pragma unroll
        for (int nt = 0; nt < 4; ++nt)
          acc[mt][nt] = __builtin_amdgcn_mfma_f32_16x16x32_bf16(
              av[mt], bv[nt], acc[mt][nt], 0, 0, 0);
    }
    __syncthreads();
  }

  // epilogue: C/D layout col=lane&15, row=(lane>>4)*4+reg  [m89/m91]
#pragma unroll
  for (int nt = 0; nt < 4; ++nt) {
    long gn = col0 + wn * 64 + nt * 16 + l15;
    float bvl = bf2f(bias[gn]);
#pragma unroll
    for (int mt = 0; mt < 4; ++mt) {
      long gm0 = row0 + wm * 64 + mt * 16 + lq * 4;
#pragma unroll
      for (int r = 0; r < 4; ++r) {
        long gm = gm0 + r;
        if (gm < M) {
          float v = acc[mt][nt][r] + bvl;
          if (EPI == 1) v = v > 0.f ? v : 0.f;
          if (EPI == 2)
            ((float*)Cout)[gm * N + gn] = v;
          else
            ((unsigned short*)Cout)[gm * N + gn] = f2bf(v);
        }
      }
    }
  }
}

// layer-1 scatter over one 64-col slice of x (dtype-dispatched read)
__global__ void scatter_x(const void* __restrict__ X,
                          const int* __restrict__ src,
                          const int* __restrict__ dst,
                          float* __restrict__ agg, int coff,
                          const int* __restrict__ flags) {
  int e = blockIdx.x * 4 + (threadIdx.x >> 6);
  int t = threadIdx.x & 63;
  if (e >= N_EDGES) return;
  int s = src[e], d = dst[e];
  long off = (long)s * D_IN + coff + t;
  float v = flags[0] ? ((const float*)X)[off]
                     : bf2f(((const unsigned short*)X)[off]);
  atomicAdd(&agg[(long)d * 64 + t], v);
}

// h[:, coff:coff+64] = bf16(x + agg) (x dtype-dispatched; h row stride D_IN)
__global__ void h_cols(const void* __restrict__ X, const float* __restrict__ agg,
                       unsigned short* __restrict__ h, int coff,
                       const int* __restrict__ flags) {
  long i = (long)blockIdx.x * 256 + threadIdx.x;
  if (i < (long)N_NODES * 64) {
    long node = i >> 6;
    int c = (int)(i & 63);
    long off = node * D_IN + coff + c;
    float xv = flags[0] ? ((const float*)X)[off]
                        : bf2f(((const unsigned short*)X)[off]);
    h[off] = f2bf(xv + agg[i]);
  }
}

// layer-2 scatter on bf16 Q over one 64-col slice
__global__ void scatter_q(const unsigned short* __restrict__ X,
                          const int* __restrict__ src,
                          const int* __restrict__ dst,
                          float* __restrict__ agg, int coff) {
  int e = blockIdx.x * 4 + (threadIdx.x >> 6);
  int t = threadIdx.x & 63;
  if (e >= N_EDGES) return;
  int s = src[e], d = dst[e];
  float v = bf2f(X[(long)s * HID + coff + t]);
  atomicAdd(&agg[(long)d * 64 + t], v);
}

// Q[:, coff:coff+64] += agg (bf16 <- bf16 + f32, in place)
__global__ void add_cols(unsigned short* __restrict__ X,
                         const float* __restrict__ agg, int coff) {
  long i = (long)blockIdx.x * 256 + threadIdx.x;
  if (i < (long)N_NODES * 64) {
    long node = i >> 6;
    int c = (int)(i & 63);
    long xi = node * HID + coff + c;
    X[xi] = f2bf(bf2f(X[xi]) + agg[i]);
  }
}

// one wave per node; lane = class (64 == wave width); f32 output
__global__ void log_softmax_64(const float* __restrict__ logits,
                               float* __restrict__ out, int n) {
  int node = blockIdx.x * 4 + (threadIdx.x >> 6);
  int c = threadIdx.x & 63;
  if (node >= n) return;
  float v = logits[(long)node * N_CLASSES + c];
  float m = v;
#pragma unroll
  for (int o = 32; o; o >>= 1) m = fmaxf(m, __shfl_xor(m, o, 64));
  float e = expf(v - m);
  float s = e;
#pragma unroll
  for (int o = 32; o; o >>= 1) s += __shfl_xor(s, o, 64);
  out[(long)node * N_CLASSES + c] = v - m - logf(s);
}

extern "C" void kernel_launch(void* const* d_in, const int* in_sizes, int n_in,
                              void* d_out, int out_size, void* d_ws,
                              size_t ws_size, hipStream_t stream) {
  const void* x = d_in[0];
  const unsigned int* ei = (const unsigned int*)d_in[1];
  const void* W1a = d_in[2];
  const void* b1a = d_in[3];
  const void* W1b = d_in[4];
  const void* b1b = d_in[5];
  const void* W2a = d_in[6];
  const void* b2a = d_in[7];
  const void* W2b = d_in[8];
  const void* b2b = d_in[9];
  const void* Wfc = d_in[10];
  const void* bfc = d_in[11];

  // ---- workspace overlay, peak ~243 MB (ran without fault in R3/R4) ----
  char* wsb = (char*)d_ws;
  const size_t Q_OFF = 0;
  const size_t HOFF = (size_t)N_NODES * (HID - D_IN);  // ushort offset in Q
  const size_t AGG_OFF = 204800000;
  const size_t LOG_OFF = 230400000;
  const size_t W_OFF = 233600000;
  const size_t B_OFF = 240546816;
  const size_t E_OFF = 240555136;
  const size_t F_OFF = 242955136;
  unsigned short* Q = (unsigned short*)(wsb + Q_OFF);
  unsigned short* hQ = Q + HOFF;
  float* aggf = (float*)(wsb + AGG_OFF);
  unsigned short* T1 = (unsigned short*)(wsb + AGG_OFF);
  float* logitsF = (float*)(wsb + LOG_OFF);
  unsigned short* W1aT = (unsigned short*)(wsb + W_OFF);
  unsigned short* W1bT = W1aT + (size_t)D_IN * HID;
  unsigned short* W2aT = W1bT + (size_t)HID * HID;
  unsigned short* W2bT = W2aT + (size_t)HID * HID;
  unsigned short* WfcT = W2bT + (size_t)HID * HID;
  unsigned short* bb1a = (unsigned short*)(wsb + B_OFF);
  unsigned short* bb1b = bb1a + HID;
  unsigned short* bb2a = bb1b + HID;
  unsigned short* bb2b = bb2a + HID;
  unsigned short* bbfc = bb2b + HID;
  int* src32 = (int*)(wsb + E_OFF);
  int* dst32 = src32 + N_EDGES;
  int* flags = (int*)(wsb + F_OFF);
  (void)ws_size; (void)n_in; (void)in_sizes; (void)out_size;

  // ---- dtype probe + input normalization ----
  probe_flags<<<1, 256, 0, stream>>>((const unsigned short*)W1a, ei, flags);
  cvt_edges<<<(N_EDGES + 255) / 256, 256, 0, stream>>>(ei, src32, dst32, flags);
  cvt_bias<<<4, 256, 0, stream>>>(b1a, bb1a, HID, flags);
  cvt_bias<<<4, 256, 0, stream>>>(b1b, bb1b, HID, flags);
  cvt_bias<<<4, 256, 0, stream>>>(b2a, bb2a, HID, flags);
  cvt_bias<<<4, 256, 0, stream>>>(b2b, bb2b, HID, flags);
  cvt_bias<<<1, 256, 0, stream>>>(bfc, bbfc, N_CLASSES, flags);
  transpose_dual<<<(D_IN * HID + 255) / 256, 256, 0, stream>>>(W1a, W1aT, D_IN, HID, flags);
  transpose_dual<<<(HID * HID + 255) / 256, 256, 0, stream>>>(W1b, W1bT, HID, HID, flags);
  transpose_dual<<<(HID * HID + 255) / 256, 256, 0, stream>>>(W2a, W2aT, HID, HID, flags);
  transpose_dual<<<(HID * HID + 255) / 256, 256, 0, stream>>>(W2b, W2bT, HID, HID, flags);
  transpose_dual<<<(HID * N_CLASSES + 255) / 256, 256, 0, stream>>>(Wfc, WfcT, HID, N_CLASSES, flags);

  const long aggN = (long)N_NODES * 64;
  const int sgrid = N_EDGES / 4;
  const int agrid = (int)((aggN + 255) / 256);

  // ---- layer 1 aggregation: h = x + segment_sum(x[src]->dst), 4 col passes ----
  for (int p = 0; p < D_IN / 64; ++p) {
    hipMemsetAsync(aggf, 0, aggN * 4, stream);
    scatter_x<<<sgrid, 256, 0, stream>>>(x, src32, dst32, aggf, p * 64, flags);
    h_cols<<<agrid, 256, 0, stream>>>(x, aggf, hQ, p * 64, flags);
  }

  // ---- layer 1 GEMMs, row-chunked through T1 ----
  dim3 gch((CM + 127) / 128, HID / 128);
  for (int c = 0; c < NCHUNK; ++c) {
    const unsigned short* Ac = hQ + (size_t)c * CM * D_IN;
    unsigned short* Qc = Q + (size_t)c * CM * HID;
    gemm_bt<2, 2, 1><<<gch, 256, 0, stream>>>(Ac, W1aT, bb1a, T1, CM, HID, D_IN);
    gemm_bt<2, 2, 1><<<gch, 256, 0, stream>>>(T1, W1bT, bb1b, Qc, CM, HID, HID);
  }

  // ---- layer 2 aggregation: Q += segment_sum(Q[src]->dst), 16 col passes ----
  for (int p = 0; p < HID / 64; ++p) {
    hipMemsetAsync(aggf, 0, aggN * 4, stream);
    scatter_q<<<sgrid, 256, 0, stream>>>(Q, src32, dst32, aggf, p * 64);
    add_cols<<<agrid, 256, 0, stream>>>(Q, aggf, p * 64);
  }

  // ---- layer 2 GEMMs + head + softmax, row-chunked ----
  dim3 ghead((CM + 255) / 256, 1);
  for (int c = 0; c < NCHUNK; ++c) {
    unsigned short* Qc = Q + (size_t)c * CM * HID;
    gemm_bt<2, 2, 1><<<gch, 256, 0, stream>>>(Qc, W2aT, bb2a, T1, CM, HID, HID);
    gemm_bt<2, 2, 0><<<gch, 256, 0, stream>>>(T1, W2bT, bb2b, Qc, CM, HID, HID);
    gemm_bt<4, 1, 2><<<ghead, 256, 0, stream>>>(Qc, WfcT, bbfc, logitsF, CM, N_CLASSES, HID);
    log_softmax_64<<<(CM + 3) / 4, 256, 0, stream>>>(
        logitsF, (float*)d_out + (size_t)c * CM * N_CLASSES, CM);
  }
}

// Round 6
// 3272.979 us; speedup vs baseline: 1.0001x; 1.0001x over previous
//
#include <hip/hip_runtime.h>
#include <stdint.h>

#define N_NODES 100000
#define N_EDGES 300000
#define D_IN 256
#define HID 1024
#define N_CLASSES 64
#define CM 12500      // row chunk for Tier-B GEMM phases (8 chunks)
#define NCHUNK 8

typedef __bf16 bf16x8 __attribute__((ext_vector_type(8)));
typedef float f32x4 __attribute__((ext_vector_type(4)));
typedef unsigned short u16x8 __attribute__((ext_vector_type(8)));

__device__ __forceinline__ float bf2f(unsigned short u) {
  union { unsigned int i; float f; } v; v.i = ((unsigned int)u) << 16; return v.f;
}
__device__ __forceinline__ unsigned short f2bf(float f) {
  union { float f; unsigned int i; } v; v.f = f;
  unsigned int u = v.i;
  unsigned int r = (u + 0x7FFFu + ((u >> 16) & 1u)) >> 16;  // RNE
  return (unsigned short)r;
}

// async global->LDS, 16B per lane; LDS dest must be wave-uniform base,
// 16B-aligned (alignas on the LDS arrays — R2's fault was this alignment)
__device__ __forceinline__ void async16(const void* g, void* l) {
  __builtin_amdgcn_global_load_lds(
      (const __attribute__((address_space(1))) void*)g,
      (__attribute__((address_space(3))) void*)l, 16, 0, 0);
}

// ---------------------------------------------------------------------------
// dtype probe: flags[0]=1 if float tensors are f32 (vs bf16)  [R4: fires=1],
//              flags[1]=1 if edge_index is int64 (vs int32).
// ---------------------------------------------------------------------------
__global__ void probe_flags(const unsigned short* __restrict__ w,
                            const unsigned int* __restrict__ e,
                            int* __restrict__ flags) {
  __shared__ int cnt;
  __shared__ unsigned int orv;
  if (threadIdx.x == 0) { cnt = 0; orv = 0u; }
  __syncthreads();
  int c = 0;
  for (int i = threadIdx.x; i < 4096; i += 256) {
    unsigned int ex = (w[i] >> 7) & 0xFFu;
    if (ex > 123u) ++c;
  }
  atomicAdd(&cnt, c);
  unsigned int o = 0;
  for (int j = threadIdx.x; j < 1000; j += 256) o |= e[2 * j + 1];
  atomicOr(&orv, o);
  __syncthreads();
  if (threadIdx.x == 0) {
    flags[0] = (cnt > 64) ? 1 : 0;
    flags[1] = (orv == 0u) ? 1 : 0;
  }
}

__global__ void cvt_edges(const unsigned int* __restrict__ ei,
                          int* __restrict__ src32, int* __restrict__ dst32,
                          const int* __restrict__ flags) {
  int i = blockIdx.x * 256 + threadIdx.x;
  if (i >= N_EDGES) return;
  if (flags[1]) {
    src32[i] = (int)ei[2 * i];
    dst32[i] = (int)ei[2 * (size_t)N_EDGES + 2 * i];
  } else {
    src32[i] = (int)ei[i];
    dst32[i] = (int)ei[N_EDGES + i];
  }
}

__global__ void transpose_dual(const void* __restrict__ W,
                               unsigned short* __restrict__ Wt, int K, int N,
                               const int* __restrict__ flags) {
  long idx = (long)blockIdx.x * 256 + threadIdx.x;
  if (idx < (long)K * N) {
    int k = (int)(idx / N), n = (int)(idx % N);
    unsigned short v = flags[0] ? f2bf(((const float*)W)[idx])
                                : ((const unsigned short*)W)[idx];
    Wt[(long)n * K + k] = v;
  }
}

__global__ void cvt_bias(const void* __restrict__ b,
                         unsigned short* __restrict__ bb, int n,
                         const int* __restrict__ flags) {
  int i = blockIdx.x * 256 + threadIdx.x;
  if (i < n)
    bb[i] = flags[0] ? f2bf(((const float*)b)[i]) : ((const unsigned short*)b)[i];
}

// ---------------- CSR build (counting sort by dst) ----------------
__global__ void hist_deg(const int* __restrict__ dst, int* __restrict__ deg) {
  int e = blockIdx.x * 256 + threadIdx.x;
  if (e < N_EDGES) atomicAdd(&deg[dst[e]], 1);
}

// single-block inclusive scan; rowptr[i+1]=scan(deg)[i], cursor[i]=rowptr[i]
__global__ void scan_deg(const int* __restrict__ deg, int* __restrict__ rowptr,
                         int* __restrict__ cursor) {
  __shared__ int lds[1024];
  __shared__ int carry_s;
  if (threadIdx.x == 0) { carry_s = 0; rowptr[0] = 0; }
  __syncthreads();
  for (int base = 0; base < N_NODES; base += 1024) {
    int i = base + threadIdx.x;
    int v = (i < N_NODES) ? deg[i] : 0;
    lds[threadIdx.x] = v;
    __syncthreads();
    for (int off = 1; off < 1024; off <<= 1) {
      int t = (threadIdx.x >= off) ? lds[threadIdx.x - off] : 0;
      __syncthreads();
      lds[threadIdx.x] += t;
      __syncthreads();
    }
    int carry = carry_s;
    if (i < N_NODES) {
      rowptr[i + 1] = carry + lds[threadIdx.x];
      cursor[i] = carry + lds[threadIdx.x] - v;
    }
    __syncthreads();
    if (threadIdx.x == 1023) carry_s = carry + lds[1023];
    __syncthreads();
  }
}

__global__ void fill_csr(const int* __restrict__ src, const int* __restrict__ dst,
                         int* __restrict__ cursor, int* __restrict__ csr) {
  int e = blockIdx.x * 256 + threadIdx.x;
  if (e < N_EDGES) {
    int pos = atomicAdd(&cursor[dst[e]], 1);
    csr[pos] = src[e];
  }
}

// ---- atomic-free aggregation, one wave per node, full feature width ----
// layer 1: h[n] = x[n] + sum_j x[csr[j]]  (x f32 or bf16; 256 cols, 4/lane)
__global__ void agg1_full(const void* __restrict__ X,
                          const int* __restrict__ rowptr,
                          const int* __restrict__ csr,
                          unsigned short* __restrict__ h,
                          const int* __restrict__ flags) {
  int node = blockIdx.x * 4 + (threadIdx.x >> 6);
  int lane = threadIdx.x & 63;
  if (node >= N_NODES) return;
  bool isf32 = flags[0] != 0;
  float acc[4];
  if (isf32) {
    float4 v = ((const float4*)((const float*)X + (long)node * D_IN))[lane];
    acc[0] = v.x; acc[1] = v.y; acc[2] = v.z; acc[3] = v.w;
  } else {
    ushort4 v = ((const ushort4*)((const unsigned short*)X + (long)node * D_IN))[lane];
    acc[0] = bf2f(v.x); acc[1] = bf2f(v.y); acc[2] = bf2f(v.z); acc[3] = bf2f(v.w);
  }
  int e0 = rowptr[node], e1 = rowptr[node + 1];
  for (int j = e0; j < e1; ++j) {
    int s = csr[j];
    if (isf32) {
      float4 v = ((const float4*)((const float*)X + (long)s * D_IN))[lane];
      acc[0] += v.x; acc[1] += v.y; acc[2] += v.z; acc[3] += v.w;
    } else {
      ushort4 v = ((const ushort4*)((const unsigned short*)X + (long)s * D_IN))[lane];
      acc[0] += bf2f(v.x); acc[1] += bf2f(v.y); acc[2] += bf2f(v.z); acc[3] += bf2f(v.w);
    }
  }
  ushort4 o;
  o.x = f2bf(acc[0]); o.y = f2bf(acc[1]); o.z = f2bf(acc[2]); o.w = f2bf(acc[3]);
  ((ushort4*)(h + (long)node * D_IN))[lane] = o;
}

// layer 2: Out[n] = Q[n] + sum_j Q[csr[j]]  (bf16, 1024 cols, 16/lane)
__global__ void agg2_full(const unsigned short* __restrict__ Q,
                          const int* __restrict__ rowptr,
                          const int* __restrict__ csr,
                          unsigned short* __restrict__ Out) {
  int node = blockIdx.x * 4 + (threadIdx.x >> 6);
  int lane = threadIdx.x & 63;
  if (node >= N_NODES) return;
  const u16x8* qs = (const u16x8*)(Q + (long)node * HID + lane * 16);
  float acc[16];
  u16x8 a = qs[0], b = qs[1];
#pragma unroll
  for (int k = 0; k < 8; ++k) { acc[k] = bf2f(a[k]); acc[8 + k] = bf2f(b[k]); }
  int e0 = rowptr[node], e1 = rowptr[node + 1];
  for (int j = e0; j < e1; ++j) {
    int s = csr[j];
    const u16x8* ps = (const u16x8*)(Q + (long)s * HID + lane * 16);
    u16x8 c = ps[0], d = ps[1];
#pragma unroll
    for (int k = 0; k < 8; ++k) { acc[k] += bf2f(c[k]); acc[8 + k] += bf2f(d[k]); }
  }
  u16x8 o0, o1;
#pragma unroll
  for (int k = 0; k < 8; ++k) { o0[k] = f2bf(acc[k]); o1[k] = f2bf(acc[8 + k]); }
  u16x8* os = (u16x8*)(Out + (long)node * HID + lane * 16);
  os[0] = o0; os[1] = o1;
}

// ---------------------------------------------------------------------------
// GEMM: C[M,N] = A[M,K] @ Bt[N,K]^T + bias(bf16), optional relu. (R5-verified)
// ---------------------------------------------------------------------------
template <int WGM, int WGN, int EPI>
__global__ __launch_bounds__(256, 2) void gemm_bt(
    const unsigned short* __restrict__ A, const unsigned short* __restrict__ Bt,
    const unsigned short* __restrict__ bias, void* __restrict__ Cout,
    int M, int N, int K) {
  constexpr int BM = WGM * 64;
  constexpr int BN = WGN * 64;
  __shared__ alignas(16) unsigned short ldsA[BM * 64];
  __shared__ alignas(16) unsigned short ldsB[BN * 64];
  const int tid = threadIdx.x;
  const int lane = tid & 63;
  const int w = tid >> 6;
  const int wm = w % WGM;
  const int wn = w / WGM;
  const long row0 = (long)blockIdx.x * BM;
  const long col0 = (long)blockIdx.y * BN;
  const int l15 = lane & 15, lq = lane >> 4;

  f32x4 acc[4][4];
#pragma unroll
  for (int i = 0; i < 4; ++i)
#pragma unroll
    for (int j = 0; j < 4; ++j) acc[i][j] = f32x4{0.f, 0.f, 0.f, 0.f};

  for (int k0 = 0; k0 < K; k0 += 64) {
#pragma unroll
    for (int i = 0; i < BM * 8 / 256; ++i) {
      int t = i * 256 + tid;
      int r = t >> 3, c = t & 7;
      long gr = row0 + r;
      if (gr >= M) gr = M - 1;
      const unsigned short* g = A + gr * (long)K + k0 + ((c ^ (r & 7)) << 3);
      void* l = (char*)ldsA + (size_t)(i * 256 + (tid & ~63)) * 16;
      async16(g, l);
    }
#pragma unroll
    for (int i = 0; i < BN * 8 / 256; ++i) {
      int t = i * 256 + tid;
      int r = t >> 3, c = t & 7;
      long gr = col0 + r;
      const unsigned short* g = Bt + gr * (long)K + k0 + ((c ^ (r & 7)) << 3);
      void* l = (char*)ldsB + (size_t)(i * 256 + (tid & ~63)) * 16;
      async16(g, l);
    }
    __syncthreads();
#pragma unroll
    for (int kk = 0; kk < 64; kk += 32) {
      bf16x8 av[4], bv[4];
#pragma unroll
      for (int mt = 0; mt < 4; ++mt) {
        int m = wm * 64 + mt * 16 + l15;
        int jj = ((kk >> 3) + lq) ^ (m & 7);
        av[mt] = *(const bf16x8*)(ldsA + m * 64 + jj * 8);
      }
#pragma unroll
      for (int nt = 0; nt < 4; ++nt) {
        int n = wn * 64 + nt * 16 + l15;
        int jj = ((kk >> 3) + lq) ^ (n & 7);
        bv[nt] = *(const bf16x8*)(ldsB + n * 64 + jj * 8);
      }
#pragma unroll
      for (int mt = 0; mt < 4; ++mt)
#pragma unroll
        for (int nt = 0; nt < 4; ++nt)
          acc[mt][nt] = __builtin_amdgcn_mfma_f32_16x16x32_bf16(
              av[mt], bv[nt], acc[mt][nt], 0, 0, 0);
    }
    __syncthreads();
  }

#pragma unroll
  for (int nt = 0; nt < 4; ++nt) {
    long gn = col0 + wn * 64 + nt * 16 + l15;
    float bvl = bf2f(bias[gn]);
#pragma unroll
    for (int mt = 0; mt < 4; ++mt) {
      long gm0 = row0 + wm * 64 + mt * 16 + lq * 4;
#pragma unroll
      for (int r = 0; r < 4; ++r) {
        long gm = gm0 + r;
        if (gm < M) {
          float v = acc[mt][nt][r] + bvl;
          if (EPI == 1) v = v > 0.f ? v : 0.f;
          if (EPI == 2)
            ((float*)Cout)[gm * N + gn] = v;
          else
            ((unsigned short*)Cout)[gm * N + gn] = f2bf(v);
        }
      }
    }
  }
}

// ---------------- Tier-B (R5) scatter path, kept as fallback ----------------
__global__ void scatter_x(const void* __restrict__ X, const int* __restrict__ src,
                          const int* __restrict__ dst, float* __restrict__ agg,
                          int coff, const int* __restrict__ flags) {
  int e = blockIdx.x * 4 + (threadIdx.x >> 6);
  int t = threadIdx.x & 63;
  if (e >= N_EDGES) return;
  int s = src[e], d = dst[e];
  long off = (long)s * D_IN + coff + t;
  float v = flags[0] ? ((const float*)X)[off] : bf2f(((const unsigned short*)X)[off]);
  atomicAdd(&agg[(long)d * 64 + t], v);
}
__global__ void h_cols(const void* __restrict__ X, const float* __restrict__ agg,
                       unsigned short* __restrict__ h, int coff,
                       const int* __restrict__ flags) {
  long i = (long)blockIdx.x * 256 + threadIdx.x;
  if (i < (long)N_NODES * 64) {
    long node = i >> 6;
    int c = (int)(i & 63);
    long off = node * D_IN + coff + c;
    float xv = flags[0] ? ((const float*)X)[off] : bf2f(((const unsigned short*)X)[off]);
    h[off] = f2bf(xv + agg[i]);
  }
}
__global__ void scatter_q(const unsigned short* __restrict__ X,
                          const int* __restrict__ src, const int* __restrict__ dst,
                          float* __restrict__ agg, int coff) {
  int e = blockIdx.x * 4 + (threadIdx.x >> 6);
  int t = threadIdx.x & 63;
  if (e >= N_EDGES) return;
  int s = src[e], d = dst[e];
  float v = bf2f(X[(long)s * HID + coff + t]);
  atomicAdd(&agg[(long)d * 64 + t], v);
}
__global__ void add_cols(unsigned short* __restrict__ X,
                         const float* __restrict__ agg, int coff) {
  long i = (long)blockIdx.x * 256 + threadIdx.x;
  if (i < (long)N_NODES * 64) {
    long node = i >> 6;
    int c = (int)(i & 63);
    long xi = node * HID + coff + c;
    X[xi] = f2bf(bf2f(X[xi]) + agg[i]);
  }
}

// one wave per node; lane = class; f32 output (R5-verified)
__global__ void log_softmax_64(const float* __restrict__ logits,
                               float* __restrict__ out, int n) {
  int node = blockIdx.x * 4 + (threadIdx.x >> 6);
  int c = threadIdx.x & 63;
  if (node >= n) return;
  float v = logits[(long)node * N_CLASSES + c];
  float m = v;
#pragma unroll
  for (int o = 32; o; o >>= 1) m = fmaxf(m, __shfl_xor(m, o, 64));
  float e = expf(v - m);
  float s = e;
#pragma unroll
  for (int o = 32; o; o >>= 1) s += __shfl_xor(s, o, 64);
  out[(long)node * N_CLASSES + c] = v - m - logf(s);
}

extern "C" void kernel_launch(void* const* d_in, const int* in_sizes, int n_in,
                              void* d_out, int out_size, void* d_ws,
                              size_t ws_size, hipStream_t stream) {
  const void* x = d_in[0];
  const unsigned int* ei = (const unsigned int*)d_in[1];
  const void* W1a = d_in[2];
  const void* b1a = d_in[3];
  const void* W1b = d_in[4];
  const void* b1b = d_in[5];
  const void* W2a = d_in[6];
  const void* b2a = d_in[7];
  const void* W2b = d_in[8];
  const void* b2b = d_in[9];
  const void* Wfc = d_in[10];
  const void* bfc = d_in[11];
  (void)n_in; (void)in_sizes; (void)out_size;

  char* wsb = (char*)d_ws;
  const bool tierA = ws_size >= 474000000ull;

  if (tierA) {
    // ---- Tier A overlay (~473 MB) ----
    unsigned short* Q = (unsigned short*)(wsb + 0);            // bf16 N*1024
    unsigned short* P = (unsigned short*)(wsb + 204800000);    // bf16 N*1024
    unsigned short* h = (unsigned short*)(wsb + 409600000);    // bf16 N*256
    float* logitsF = (float*)(wsb + 409600000);                // f32 N*64 (h dead)
    unsigned short* W1aT = (unsigned short*)(wsb + 460800000);
    unsigned short* W1bT = W1aT + (size_t)D_IN * HID;
    unsigned short* W2aT = W1bT + (size_t)HID * HID;
    unsigned short* W2bT = W2aT + (size_t)HID * HID;
    unsigned short* WfcT = W2bT + (size_t)HID * HID;           // ends 467,746,816
    unsigned short* bb1a = (unsigned short*)(wsb + 467746816);
    unsigned short* bb1b = bb1a + HID;
    unsigned short* bb2a = bb1b + HID;
    unsigned short* bb2b = bb2a + HID;
    unsigned short* bbfc = bb2b + HID;
    int* src32 = (int*)(wsb + 467755136);
    int* dst32 = src32 + N_EDGES;
    int* rowptr = (int*)(wsb + 470155136);   // N+1
    int* cursor = rowptr + (N_NODES + 4);
    int* deg = cursor + N_NODES;
    int* csr = deg + N_NODES;                // N_EDGES
    int* flags = csr + N_EDGES;              // ends ~473.0 MB

    probe_flags<<<1, 256, 0, stream>>>((const unsigned short*)W1a, ei, flags);
    cvt_edges<<<(N_EDGES + 255) / 256, 256, 0, stream>>>(ei, src32, dst32, flags);
    hipMemsetAsync(deg, 0, (size_t)N_NODES * 4, stream);
    hist_deg<<<(N_EDGES + 255) / 256, 256, 0, stream>>>(dst32, deg);
    scan_deg<<<1, 1024, 0, stream>>>(deg, rowptr, cursor);
    fill_csr<<<(N_EDGES + 255) / 256, 256, 0, stream>>>(src32, dst32, cursor, csr);
    cvt_bias<<<4, 256, 0, stream>>>(b1a, bb1a, HID, flags);
    cvt_bias<<<4, 256, 0, stream>>>(b1b, bb1b, HID, flags);
    cvt_bias<<<4, 256, 0, stream>>>(b2a, bb2a, HID, flags);
    cvt_bias<<<4, 256, 0, stream>>>(b2b, bb2b, HID, flags);
    cvt_bias<<<1, 256, 0, stream>>>(bfc, bbfc, N_CLASSES, flags);
    transpose_dual<<<(D_IN * HID + 255) / 256, 256, 0, stream>>>(W1a, W1aT, D_IN, HID, flags);
    transpose_dual<<<(HID * HID + 255) / 256, 256, 0, stream>>>(W1b, W1bT, HID, HID, flags);
    transpose_dual<<<(HID * HID + 255) / 256, 256, 0, stream>>>(W2a, W2aT, HID, HID, flags);
    transpose_dual<<<(HID * HID + 255) / 256, 256, 0, stream>>>(W2b, W2bT, HID, HID, flags);
    transpose_dual<<<(HID * N_CLASSES + 255) / 256, 256, 0, stream>>>(Wfc, WfcT, HID, N_CLASSES, flags);

    const int ngrid = (N_NODES + 3) / 4;
    dim3 gmain((N_NODES + 127) / 128, HID / 128);   // 782 x 8
    dim3 ghead((N_NODES + 255) / 256, 1);           // 391

    agg1_full<<<ngrid, 256, 0, stream>>>(x, rowptr, csr, h, flags);
    gemm_bt<2, 2, 1><<<gmain, 256, 0, stream>>>(h, W1aT, bb1a, P, N_NODES, HID, D_IN);
    gemm_bt<2, 2, 1><<<gmain, 256, 0, stream>>>(P, W1bT, bb1b, Q, N_NODES, HID, HID);
    agg2_full<<<ngrid, 256, 0, stream>>>(Q, rowptr, csr, P);   // P free here
    gemm_bt<2, 2, 1><<<gmain, 256, 0, stream>>>(P, W2aT, bb2a, Q, N_NODES, HID, HID);
    gemm_bt<2, 2, 0><<<gmain, 256, 0, stream>>>(Q, W2bT, bb2b, P, N_NODES, HID, HID);
    gemm_bt<4, 1, 2><<<ghead, 256, 0, stream>>>(P, WfcT, bbfc, logitsF, N_NODES, N_CLASSES, HID);
    log_softmax_64<<<ngrid, 256, 0, stream>>>(logitsF, (float*)d_out, N_NODES);
    return;
  }

  // ---- Tier B: exact R5 path (verified PASS at 3273 us) ----
  const size_t Q_OFF = 0;
  const size_t HOFF = (size_t)N_NODES * (HID - D_IN);
  const size_t AGG_OFF = 204800000;
  const size_t LOG_OFF = 230400000;
  const size_t W_OFF = 233600000;
  const size_t B_OFF = 240546816;
  const size_t E_OFF = 240555136;
  const size_t F_OFF = 242955136;
  unsigned short* Q = (unsigned short*)(wsb + Q_OFF);
  unsigned short* hQ = Q + HOFF;
  float* aggf = (float*)(wsb + AGG_OFF);
  unsigned short* T1 = (unsigned short*)(wsb + AGG_OFF);
  float* logitsF = (float*)(wsb + LOG_OFF);
  unsigned short* W1aT = (unsigned short*)(wsb + W_OFF);
  unsigned short* W1bT = W1aT + (size_t)D_IN * HID;
  unsigned short* W2aT = W1bT + (size_t)HID * HID;
  unsigned short* W2bT = W2aT + (size_t)HID * HID;
  unsigned short* WfcT = W2bT + (size_t)HID * HID;
  unsigned short* bb1a = (unsigned short*)(wsb + B_OFF);
  unsigned short* bb1b = bb1a + HID;
  unsigned short* bb2a = bb1b + HID;
  unsigned short* bb2b = bb2a + HID;
  unsigned short* bbfc = bb2b + HID;
  int* src32 = (int*)(wsb + E_OFF);
  int* dst32 = src32 + N_EDGES;
  int* flags = (int*)(wsb + F_OFF);

  probe_flags<<<1, 256, 0, stream>>>((const unsigned short*)W1a, ei, flags);
  cvt_edges<<<(N_EDGES + 255) / 256, 256, 0, stream>>>(ei, src32, dst32, flags);
  cvt_bias<<<4, 256, 0, stream>>>(b1a, bb1a, HID, flags);
  cvt_bias<<<4, 256, 0, stream>>>(b1b, bb1b, HID, flags);
  cvt_bias<<<4, 256, 0, stream>>>(b2a, bb2a, HID, flags);
  cvt_bias<<<4, 256, 0, stream>>>(b2b, bb2b, HID, flags);
  cvt_bias<<<1, 256, 0, stream>>>(bfc, bbfc, N_CLASSES, flags);
  transpose_dual<<<(D_IN * HID + 255) / 256, 256, 0, stream>>>(W1a, W1aT, D_IN, HID, flags);
  transpose_dual<<<(HID * HID + 255) / 256, 256, 0, stream>>>(W1b, W1bT, HID, HID, flags);
  transpose_dual<<<(HID * HID + 255) / 256, 256, 0, stream>>>(W2a, W2aT, HID, HID, flags);
  transpose_dual<<<(HID * HID + 255) / 256, 256, 0, stream>>>(W2b, W2bT, HID, HID, flags);
  transpose_dual<<<(HID * N_CLASSES + 255) / 256, 256, 0, stream>>>(Wfc, WfcT, HID, N_CLASSES, flags);

  const long aggN = (long)N_NODES * 64;
  const int sgrid = N_EDGES / 4;
  const int agrid = (int)((aggN + 255) / 256);

  for (int p = 0; p < D_IN / 64; ++p) {
    hipMemsetAsync(aggf, 0, aggN * 4, stream);
    scatter_x<<<sgrid, 256, 0, stream>>>(x, src32, dst32, aggf, p * 64, flags);
    h_cols<<<agrid, 256, 0, stream>>>(x, aggf, hQ, p * 64, flags);
  }
  dim3 gch((CM + 127) / 128, HID / 128);
  for (int c = 0; c < NCHUNK; ++c) {
    const unsigned short* Ac = hQ + (size_t)c * CM * D_IN;
    unsigned short* Qc = Q + (size_t)c * CM * HID;
    gemm_bt<2, 2, 1><<<gch, 256, 0, stream>>>(Ac, W1aT, bb1a, T1, CM, HID, D_IN);
    gemm_bt<2, 2, 1><<<gch, 256, 0, stream>>>(T1, W1bT, bb1b, Qc, CM, HID, HID);
  }
  for (int p = 0; p < HID / 64; ++p) {
    hipMemsetAsync(aggf, 0, aggN * 4, stream);
    scatter_q<<<sgrid, 256, 0, stream>>>(Q, src32, dst32, aggf, p * 64);
    add_cols<<<agrid, 256, 0, stream>>>(Q, aggf, p * 64);
  }
  dim3 ghead((CM + 255) / 256, 1);
  for (int c = 0; c < NCHUNK; ++c) {
    unsigned short* Qc = Q + (size_t)c * CM * HID;
    gemm_bt<2, 2, 1><<<gch, 256, 0, stream>>>(Qc, W2aT, bb2a, T1, CM, HID, HID);
    gemm_bt<2, 2, 0><<<gch, 256, 0, stream>>>(T1, W2bT, bb2b, Qc, CM, HID, HID);
    gemm_bt<4, 1, 2><<<ghead, 256, 0, stream>>>(Qc, WfcT, bbfc, logitsF, CM, N_CLASSES, HID);
    log_softmax_64<<<(CM + 3) / 4, 256, 0, stream>>>(
        logitsF, (float*)d_out + (size_t)c * CM * N_CLASSES, CM);
  }
}

// Round 7
// 2215.568 us; speedup vs baseline: 1.4774x; 1.4773x over previous
//
#include <hip/hip_runtime.h>
#include <stdint.h>

#define N_NODES 100000
#define N_EDGES 300000
#define D_IN 256
#define HID 1024
#define N_CLASSES 64
#define CM 12500      // row chunk for GEMM phases (8 chunks)
#define NCHUNK 8

typedef __bf16 bf16x8 __attribute__((ext_vector_type(8)));
typedef float f32x4 __attribute__((ext_vector_type(4)));

__device__ __forceinline__ float bf2f(unsigned short u) {
  union { unsigned int i; float f; } v; v.i = ((unsigned int)u) << 16; return v.f;
}
__device__ __forceinline__ unsigned short f2bf(float f) {
  union { float f; unsigned int i; } v; v.f = f;
  unsigned int u = v.i;
  unsigned int r = (u + 0x7FFFu + ((u >> 16) & 1u)) >> 16;  // RNE
  return (unsigned short)r;
}

// async global->LDS, 16B per lane; LDS dest wave-uniform base, 16B-aligned
__device__ __forceinline__ void async16(const void* g, void* l) {
  __builtin_amdgcn_global_load_lds(
      (const __attribute__((address_space(1))) void*)g,
      (__attribute__((address_space(3))) void*)l, 16, 0, 0);
}

// ---------------------------------------------------------------------------
// dtype probe: flags[0]=1 if float tensors are f32 (vs bf16)  [R4/R5: =1],
//              flags[1]=1 if edge_index is int64 (vs int32).
// ---------------------------------------------------------------------------
__global__ void probe_flags(const unsigned short* __restrict__ w,
                            const unsigned int* __restrict__ e,
                            int* __restrict__ flags) {
  __shared__ int cnt;
  __shared__ unsigned int orv;
  if (threadIdx.x == 0) { cnt = 0; orv = 0u; }
  __syncthreads();
  int c = 0;
  for (int i = threadIdx.x; i < 4096; i += 256) {
    unsigned int ex = (w[i] >> 7) & 0xFFu;
    if (ex > 123u) ++c;
  }
  atomicAdd(&cnt, c);
  unsigned int o = 0;
  for (int j = threadIdx.x; j < 1000; j += 256) o |= e[2 * j + 1];
  atomicOr(&orv, o);
  __syncthreads();
  if (threadIdx.x == 0) {
    flags[0] = (cnt > 64) ? 1 : 0;
    flags[1] = (orv == 0u) ? 1 : 0;
  }
}

__global__ void cvt_edges(const unsigned int* __restrict__ ei,
                          int* __restrict__ src32, int* __restrict__ dst32,
                          const int* __restrict__ flags) {
  int i = blockIdx.x * 256 + threadIdx.x;
  if (i >= N_EDGES) return;
  if (flags[1]) {
    src32[i] = (int)ei[2 * i];
    dst32[i] = (int)ei[2 * (size_t)N_EDGES + 2 * i];
  } else {
    src32[i] = (int)ei[i];
    dst32[i] = (int)ei[N_EDGES + i];
  }
}

__global__ void transpose_dual(const void* __restrict__ W,
                               unsigned short* __restrict__ Wt, int K, int N,
                               const int* __restrict__ flags) {
  long idx = (long)blockIdx.x * 256 + threadIdx.x;
  if (idx < (long)K * N) {
    int k = (int)(idx / N), n = (int)(idx % N);
    unsigned short v = flags[0] ? f2bf(((const float*)W)[idx])
                                : ((const unsigned short*)W)[idx];
    Wt[(long)n * K + k] = v;
  }
}

__global__ void cvt_bias(const void* __restrict__ b,
                         unsigned short* __restrict__ bb, int n,
                         const int* __restrict__ flags) {
  int i = blockIdx.x * 256 + threadIdx.x;
  if (i < n)
    bb[i] = flags[0] ? f2bf(((const float*)b)[i]) : ((const unsigned short*)b)[i];
}

// ---------------- CSR build (counting sort by dst) ----------------
__global__ void hist_deg(const int* __restrict__ dst, int* __restrict__ deg) {
  int e = blockIdx.x * 256 + threadIdx.x;
  if (e < N_EDGES) atomicAdd(&deg[dst[e]], 1);
}

// single-block scan: rowptr[i+1]=incl_scan(deg)[i], cursor[i]=excl prefix
__global__ void scan_deg(const int* __restrict__ deg, int* __restrict__ rowptr,
                         int* __restrict__ cursor) {
  __shared__ int lds[1024];
  __shared__ int carry_s;
  if (threadIdx.x == 0) { carry_s = 0; rowptr[0] = 0; }
  __syncthreads();
  for (int base = 0; base < N_NODES; base += 1024) {
    int i = base + threadIdx.x;
    int v = (i < N_NODES) ? deg[i] : 0;
    lds[threadIdx.x] = v;
    __syncthreads();
    for (int off = 1; off < 1024; off <<= 1) {
      int t = (threadIdx.x >= off) ? lds[threadIdx.x - off] : 0;
      __syncthreads();
      lds[threadIdx.x] += t;
      __syncthreads();
    }
    int carry = carry_s;
    if (i < N_NODES) {
      rowptr[i + 1] = carry + lds[threadIdx.x];
      cursor[i] = carry + lds[threadIdx.x] - v;
    }
    __syncthreads();
    if (threadIdx.x == 1023) carry_s = carry + lds[1023];
    __syncthreads();
  }
}

__global__ void fill_csr(const int* __restrict__ src, const int* __restrict__ dst,
                         int* __restrict__ cursor, int* __restrict__ csr) {
  int e = blockIdx.x * 256 + threadIdx.x;
  if (e < N_EDGES) {
    int pos = atomicAdd(&cursor[dst[e]], 1);
    csr[pos] = src[e];
  }
}

// ---- atomic-free aggregation, one wave per node ----
// layer 1: h[n] = bf16(x[n] + sum_j x[csr[j]])  (x f32 or bf16; 4 cols/lane)
__global__ void agg1_full(const void* __restrict__ X,
                          const int* __restrict__ rowptr,
                          const int* __restrict__ csr,
                          unsigned short* __restrict__ h,
                          const int* __restrict__ flags) {
  int node = blockIdx.x * 4 + (threadIdx.x >> 6);
  int lane = threadIdx.x & 63;
  if (node >= N_NODES) return;
  bool isf32 = flags[0] != 0;
  float acc[4];
  if (isf32) {
    float4 v = ((const float4*)((const float*)X + (long)node * D_IN))[lane];
    acc[0] = v.x; acc[1] = v.y; acc[2] = v.z; acc[3] = v.w;
  } else {
    ushort4 v = ((const ushort4*)((const unsigned short*)X + (long)node * D_IN))[lane];
    acc[0] = bf2f(v.x); acc[1] = bf2f(v.y); acc[2] = bf2f(v.z); acc[3] = bf2f(v.w);
  }
  int e0 = rowptr[node], e1 = rowptr[node + 1];
  for (int j = e0; j < e1; ++j) {
    int s = csr[j];
    if (isf32) {
      float4 v = ((const float4*)((const float*)X + (long)s * D_IN))[lane];
      acc[0] += v.x; acc[1] += v.y; acc[2] += v.z; acc[3] += v.w;
    } else {
      ushort4 v = ((const ushort4*)((const unsigned short*)X + (long)s * D_IN))[lane];
      acc[0] += bf2f(v.x); acc[1] += bf2f(v.y); acc[2] += bf2f(v.z); acc[3] += bf2f(v.w);
    }
  }
  ushort4 o;
  o.x = f2bf(acc[0]); o.y = f2bf(acc[1]); o.z = f2bf(acc[2]); o.w = f2bf(acc[3]);
  ((ushort4*)(h + (long)node * D_IN))[lane] = o;
}

// layer 2, 128-col slice: T[n][0:128] = bf16(Q[n][cb*128+c] + sum_j Q[csr[j]][...])
__global__ void agg2_cols(const unsigned short* __restrict__ Q,
                          const int* __restrict__ rowptr,
                          const int* __restrict__ csr,
                          unsigned short* __restrict__ T, int cb) {
  int node = blockIdx.x * 4 + (threadIdx.x >> 6);
  int lane = threadIdx.x & 63;
  if (node >= N_NODES) return;
  unsigned int p = ((const unsigned int*)(Q + (long)node * HID + cb * 128))[lane];
  float a0 = bf2f((unsigned short)(p & 0xFFFFu));
  float a1 = bf2f((unsigned short)(p >> 16));
  int e0 = rowptr[node], e1 = rowptr[node + 1];
  for (int j = e0; j < e1; ++j) {
    int s = csr[j];
    unsigned int q = ((const unsigned int*)(Q + (long)s * HID + cb * 128))[lane];
    a0 += bf2f((unsigned short)(q & 0xFFFFu));
    a1 += bf2f((unsigned short)(q >> 16));
  }
  unsigned int o = (unsigned int)f2bf(a0) | ((unsigned int)f2bf(a1) << 16);
  ((unsigned int*)(T + (long)node * 128))[lane] = o;
}

// Q[:, cb*128 : cb*128+128] = T  (uint4 = 8 bf16 per thread)
__global__ void copyback_cols(unsigned short* __restrict__ Q,
                              const unsigned short* __restrict__ T, int cb) {
  long i = (long)blockIdx.x * 256 + threadIdx.x;  // uint4 index
  if (i < (long)N_NODES * 16) {
    long node = i >> 4;
    int c = (int)(i & 15);
    ((uint4*)(Q + node * HID + cb * 128))[c] = ((const uint4*)T)[i];
  }
}

// ---------------------------------------------------------------------------
// GEMM: C[M,N] = A[M,K] @ Bt[N,K]^T + bias(bf16), optional relu. (R5-verified)
// ---------------------------------------------------------------------------
template <int WGM, int WGN, int EPI>
__global__ __launch_bounds__(256, 2) void gemm_bt(
    const unsigned short* __restrict__ A, const unsigned short* __restrict__ Bt,
    const unsigned short* __restrict__ bias, void* __restrict__ Cout,
    int M, int N, int K) {
  constexpr int BM = WGM * 64;
  constexpr int BN = WGN * 64;
  __shared__ alignas(16) unsigned short ldsA[BM * 64];
  __shared__ alignas(16) unsigned short ldsB[BN * 64];
  const int tid = threadIdx.x;
  const int lane = tid & 63;
  const int w = tid >> 6;
  const int wm = w % WGM;
  const int wn = w / WGM;
  const long row0 = (long)blockIdx.x * BM;
  const long col0 = (long)blockIdx.y * BN;
  const int l15 = lane & 15, lq = lane >> 4;

  f32x4 acc[4][4];
#pragma unroll
  for (int i = 0; i < 4; ++i)
#pragma unroll
    for (int j = 0; j < 4; ++j) acc[i][j] = f32x4{0.f, 0.f, 0.f, 0.f};

  for (int k0 = 0; k0 < K; k0 += 64) {
#pragma unroll
    for (int i = 0; i < BM * 8 / 256; ++i) {
      int t = i * 256 + tid;
      int r = t >> 3, c = t & 7;
      long gr = row0 + r;
      if (gr >= M) gr = M - 1;
      const unsigned short* g = A + gr * (long)K + k0 + ((c ^ (r & 7)) << 3);
      void* l = (char*)ldsA + (size_t)(i * 256 + (tid & ~63)) * 16;
      async16(g, l);
    }
#pragma unroll
    for (int i = 0; i < BN * 8 / 256; ++i) {
      int t = i * 256 + tid;
      int r = t >> 3, c = t & 7;
      long gr = col0 + r;
      const unsigned short* g = Bt + gr * (long)K + k0 + ((c ^ (r & 7)) << 3);
      void* l = (char*)ldsB + (size_t)(i * 256 + (tid & ~63)) * 16;
      async16(g, l);
    }
    __syncthreads();
#pragma unroll
    for (int kk = 0; kk < 64; kk += 32) {
      bf16x8 av[4], bv[4];
#pragma unroll
      for (int mt = 0; mt < 4; ++mt) {
        int m = wm * 64 + mt * 16 + l15;
        int jj = ((kk >> 3) + lq) ^ (m & 7);
        av[mt] = *(const bf16x8*)(ldsA + m * 64 + jj * 8);
      }
#pragma unroll
      for (int nt = 0; nt < 4; ++nt) {
        int n = wn * 64 + nt * 16 + l15;
        int jj = ((kk >> 3) + lq) ^ (n & 7);
        bv[nt] = *(const bf16x8*)(ldsB + n * 64 + jj * 8);
      }
#pragma unroll
      for (int mt = 0; mt < 4; ++mt)
#pragma unroll
        for (int nt = 0; nt < 4; ++nt)
          acc[mt][nt] = __builtin_amdgcn_mfma_f32_16x16x32_bf16(
              av[mt], bv[nt], acc[mt][nt], 0, 0, 0);
    }
    __syncthreads();
  }

#pragma unroll
  for (int nt = 0; nt < 4; ++nt) {
    long gn = col0 + wn * 64 + nt * 16 + l15;
    float bvl = bf2f(bias[gn]);
#pragma unroll
    for (int mt = 0; mt < 4; ++mt) {
      long gm0 = row0 + wm * 64 + mt * 16 + lq * 4;
#pragma unroll
      for (int r = 0; r < 4; ++r) {
        long gm = gm0 + r;
        if (gm < M) {
          float v = acc[mt][nt][r] + bvl;
          if (EPI == 1) v = v > 0.f ? v : 0.f;
          if (EPI == 2)
            ((float*)Cout)[gm * N + gn] = v;
          else
            ((unsigned short*)Cout)[gm * N + gn] = f2bf(v);
        }
      }
    }
  }
}

// one wave per node; lane = class; f32 output (R5-verified)
__global__ void log_softmax_64(const float* __restrict__ logits,
                               float* __restrict__ out, int n) {
  int node = blockIdx.x * 4 + (threadIdx.x >> 6);
  int c = threadIdx.x & 63;
  if (node >= n) return;
  float v = logits[(long)node * N_CLASSES + c];
  float m = v;
#pragma unroll
  for (int o = 32; o; o >>= 1) m = fmaxf(m, __shfl_xor(m, o, 64));
  float e = expf(v - m);
  float s = e;
#pragma unroll
  for (int o = 32; o; o >>= 1) s += __shfl_xor(s, o, 64);
  out[(long)node * N_CLASSES + c] = v - m - logf(s);
}

extern "C" void kernel_launch(void* const* d_in, const int* in_sizes, int n_in,
                              void* d_out, int out_size, void* d_ws,
                              size_t ws_size, hipStream_t stream) {
  const void* x = d_in[0];
  const unsigned int* ei = (const unsigned int*)d_in[1];
  const void* W1a = d_in[2];
  const void* b1a = d_in[3];
  const void* W1b = d_in[4];
  const void* b1b = d_in[5];
  const void* W2a = d_in[6];
  const void* b2a = d_in[7];
  const void* W2b = d_in[8];
  const void* b2b = d_in[9];
  const void* Wfc = d_in[10];
  const void* bfc = d_in[11];
  (void)n_in; (void)in_sizes; (void)out_size; (void)ws_size;

  // ---- workspace overlay: proven-safe ~242.2 MB peak ----
  // Q_OFF 0..204.8M   : Q (bf16 N*1024); h (bf16 N*256) in tail at HOFF
  //                     (GEMM2(c) writes <=(c+1)*12.8M ushorts; h[c'] at
  //                      76.8M+c'*3.2M >= that for c<=7 — verified R5)
  // AGG_OFF +204.8M   : 25.6MB, time-shared: setup {src32,dst32,deg,cursor}
  //                     -> GEMM inter buffer T1 (CM*1024 bf16) / agg2 slice T
  // LOG_OFF +230.4M   : f32 logits chunk (CM*64), 3.2MB
  // W_OFF   +233.6M   : transposed bf16 weights (6.95MB)
  // B_OFF   +240.547M : bf16 biases
  // RP_OFF  +240.555M : rowptr (N+1 ints), then csr (N_EDGES ints), flags
  char* wsb = (char*)d_ws;
  const size_t HOFF = (size_t)N_NODES * (HID - D_IN);
  const size_t AGG_OFF = 204800000;
  const size_t LOG_OFF = 230400000;
  const size_t W_OFF = 233600000;
  const size_t B_OFF = 240546816;
  const size_t RP_OFF = 240555136;
  const size_t CSR_OFF = 240955152;
  const size_t F_OFF = 242155152;
  unsigned short* Q = (unsigned short*)(wsb + 0);
  unsigned short* hQ = Q + HOFF;
  unsigned short* T1 = (unsigned short*)(wsb + AGG_OFF);
  int* src32 = (int*)(wsb + AGG_OFF);            // setup-only, dies before T1 use
  int* dst32 = src32 + N_EDGES;
  int* deg = dst32 + N_EDGES;
  int* cursor = deg + N_NODES;
  float* logitsF = (float*)(wsb + LOG_OFF);
  unsigned short* W1aT = (unsigned short*)(wsb + W_OFF);
  unsigned short* W1bT = W1aT + (size_t)D_IN * HID;
  unsigned short* W2aT = W1bT + (size_t)HID * HID;
  unsigned short* W2bT = W2aT + (size_t)HID * HID;
  unsigned short* WfcT = W2bT + (size_t)HID * HID;
  unsigned short* bb1a = (unsigned short*)(wsb + B_OFF);
  unsigned short* bb1b = bb1a + HID;
  unsigned short* bb2a = bb1b + HID;
  unsigned short* bb2b = bb2a + HID;
  unsigned short* bbfc = bb2b + HID;
  int* rowptr = (int*)(wsb + RP_OFF);
  int* csr = (int*)(wsb + CSR_OFF);
  int* flags = (int*)(wsb + F_OFF);

  // ---- setup: dtype probe, edge/weight normalization, CSR build ----
  probe_flags<<<1, 256, 0, stream>>>((const unsigned short*)W1a, ei, flags);
  cvt_edges<<<(N_EDGES + 255) / 256, 256, 0, stream>>>(ei, src32, dst32, flags);
  hipMemsetAsync(deg, 0, (size_t)N_NODES * 4, stream);
  hist_deg<<<(N_EDGES + 255) / 256, 256, 0, stream>>>(dst32, deg);
  scan_deg<<<1, 1024, 0, stream>>>(deg, rowptr, cursor);
  fill_csr<<<(N_EDGES + 255) / 256, 256, 0, stream>>>(src32, dst32, cursor, csr);
  cvt_bias<<<4, 256, 0, stream>>>(b1a, bb1a, HID, flags);
  cvt_bias<<<4, 256, 0, stream>>>(b1b, bb1b, HID, flags);
  cvt_bias<<<4, 256, 0, stream>>>(b2a, bb2a, HID, flags);
  cvt_bias<<<4, 256, 0, stream>>>(b2b, bb2b, HID, flags);
  cvt_bias<<<1, 256, 0, stream>>>(bfc, bbfc, N_CLASSES, flags);
  transpose_dual<<<(D_IN * HID + 255) / 256, 256, 0, stream>>>(W1a, W1aT, D_IN, HID, flags);
  transpose_dual<<<(HID * HID + 255) / 256, 256, 0, stream>>>(W1b, W1bT, HID, HID, flags);
  transpose_dual<<<(HID * HID + 255) / 256, 256, 0, stream>>>(W2a, W2aT, HID, HID, flags);
  transpose_dual<<<(HID * HID + 255) / 256, 256, 0, stream>>>(W2b, W2bT, HID, HID, flags);
  transpose_dual<<<(HID * N_CLASSES + 255) / 256, 256, 0, stream>>>(Wfc, WfcT, HID, N_CLASSES, flags);

  const int ngrid = (N_NODES + 3) / 4;  // one wave per node, 4 waves/block

  // ---- layer 1 aggregation (atomic-free, one pass) ----
  agg1_full<<<ngrid, 256, 0, stream>>>(x, rowptr, csr, hQ, flags);

  // ---- layer 1 GEMMs, row-chunked through T1 (setup arrays dead now) ----
  dim3 gch((CM + 127) / 128, HID / 128);
  for (int c = 0; c < NCHUNK; ++c) {
    const unsigned short* Ac = hQ + (size_t)c * CM * D_IN;
    unsigned short* Qc = Q + (size_t)c * CM * HID;
    gemm_bt<2, 2, 1><<<gch, 256, 0, stream>>>(Ac, W1aT, bb1a, T1, CM, HID, D_IN);
    gemm_bt<2, 2, 1><<<gch, 256, 0, stream>>>(T1, W1bT, bb1b, Qc, CM, HID, HID);
  }

  // ---- layer 2 aggregation: 8 x 128-col passes through T1, atomic-free ----
  const int cgrid = (int)(((long)N_NODES * 16 + 255) / 256);
  for (int cb = 0; cb < HID / 128; ++cb) {
    agg2_cols<<<ngrid, 256, 0, stream>>>(Q, rowptr, csr, T1, cb);
    copyback_cols<<<cgrid, 256, 0, stream>>>(Q, T1, cb);
  }

  // ---- layer 2 GEMMs + head + softmax, row-chunked ----
  dim3 ghead((CM + 255) / 256, 1);
  for (int c = 0; c < NCHUNK; ++c) {
    unsigned short* Qc = Q + (size_t)c * CM * HID;
    gemm_bt<2, 2, 1><<<gch, 256, 0, stream>>>(Qc, W2aT, bb2a, T1, CM, HID, HID);
    gemm_bt<2, 2, 0><<<gch, 256, 0, stream>>>(T1, W2bT, bb2b, Qc, CM, HID, HID);
    gemm_bt<4, 1, 2><<<ghead, 256, 0, stream>>>(Qc, WfcT, bbfc, logitsF, CM, N_CLASSES, HID);
    log_softmax_64<<<(CM + 3) / 4, 256, 0, stream>>>(
        logitsF, (float*)d_out + (size_t)c * CM * N_CLASSES, CM);
  }
}